// Round 1
// baseline (453.233 us; speedup 1.0000x reference)
//
#include <hip/hip_runtime.h>

#define DIM 160
#define TILE 8
#define IN 14            // TILE + 6 halo
#define NTILE 20         // 160 / 8
#define NB 4
#define NVOX_D 16384000.0  // 4*160^3

// Gaussian weights, sigma=1.5, size 7 (precomputed, matches fp32 reference to ~1e-7)
#define W0 0.03663285f
#define W1 0.11128076f
#define W2 0.21674532f
#define W3 0.27068213f

__global__ void ssim_zero_acc(double* acc) {
    if (threadIdx.x == 0 && blockIdx.x == 0) acc[0] = 0.0;
}

__global__ __launch_bounds__(256) void ssim_main(const float* __restrict__ P,
                                                 const float* __restrict__ T,
                                                 double* __restrict__ acc) {
    const float W[7] = {W0, W1, W2, W3, W2, W1, W0};
    const float C1 = 1e-4f;   // 0.01^2
    const float C2 = 9e-4f;   // 0.03^2

    // LDS layout (53312 bytes):
    //   region A [0, 5488): sP (2744) + sT (2744)   -- dead after z-pass
    //             reused as t2 [5][8][8][14] = 4480 -- live from y-pass
    //   region B [5488, 13328): t1 [5][8][14][14] = 7840
    __shared__ float smem[13328];
    float* sIn = smem;
    float* t1  = smem + 5488;
    float* t2  = smem;

    const int tid = threadIdx.x;
    int bid = blockIdx.x;
    int b   = bid / 8000;
    int r   = bid - b * 8000;
    int tz  = r / 400;
    int r2  = r - tz * 400;
    int ty  = r2 / 20;
    int tx  = r2 - ty * 20;

    const int base = b * (DIM * DIM * DIM);
    const int z0 = tz * TILE - 3, y0 = ty * TILE - 3, x0 = tx * TILE - 3;

    // ---- load 14^3 halo tiles of P and T into LDS (zero-pad OOB = SAME conv) ----
    for (int i = tid; i < IN * IN * IN; i += 256) {
        int z  = i / (IN * IN);
        int rr = i - z * (IN * IN);
        int y  = rr / IN;
        int x  = rr - y * IN;
        int gz = z0 + z, gy = y0 + y, gx = x0 + x;
        bool ok = ((unsigned)gz < (unsigned)DIM) & ((unsigned)gy < (unsigned)DIM) &
                  ((unsigned)gx < (unsigned)DIM);
        int gi = base + (gz * DIM + gy) * DIM + gx;
        sIn[i]        = ok ? P[gi] : 0.f;
        sIn[i + 2744] = ok ? T[gi] : 0.f;
    }
    __syncthreads();

    // ---- z-pass: one thread per (y,x) column; all 5 channels in one sweep ----
    if (tid < IN * IN) {
        const int y = tid / IN;
        const int x = tid - y * IN;
        float p[IN], t[IN];
#pragma unroll
        for (int z = 0; z < IN; ++z) {
            p[z] = sIn[(z * IN + y) * IN + x];
            t[z] = sIn[2744 + (z * IN + y) * IN + x];
        }
#pragma unroll
        for (int z = 0; z < TILE; ++z) {
            float s0 = 0.f, s1 = 0.f, s2 = 0.f, s3 = 0.f, s4 = 0.f;
#pragma unroll
            for (int k = 0; k < 7; ++k) {
                float w = W[k], pp = p[z + k], tt = t[z + k];
                float wp = w * pp, wt = w * tt;
                s0 += wp;          // mu_p
                s1 += wt;          // mu_t
                s2 += wp * pp;     // E[p^2]
                s3 += wt * tt;     // E[t^2]
                s4 += wp * tt;     // E[p t]
            }
            int o = (z * IN + y) * IN + x;
            t1[o]        = s0;
            t1[o + 1568] = s1;
            t1[o + 3136] = s2;
            t1[o + 4704] = s3;
            t1[o + 6272] = s4;
        }
    }
    __syncthreads();

    // ---- y-pass: units (c,z,x) = 5*8*14 = 560 ----
    for (int u = tid; u < 560; u += 256) {
        int c  = u / 112;
        int r3 = u - c * 112;
        int z  = r3 / IN;
        int x  = r3 - z * IN;
        const float* src = &t1[c * 1568 + z * 196 + x];
        float col[IN];
#pragma unroll
        for (int yy = 0; yy < IN; ++yy) col[yy] = src[yy * IN];
        float* dst = &t2[c * 896 + z * 112 + x];
#pragma unroll
        for (int yy = 0; yy < TILE; ++yy) {
            float s = 0.f;
#pragma unroll
            for (int k = 0; k < 7; ++k) s += W[k] * col[yy + k];
            dst[yy * IN] = s;
        }
    }
    __syncthreads();

    // ---- x-pass + SSIM map, per-thread 2 voxels ----
    float lsum = 0.f;
#pragma unroll
    for (int it = 0; it < 2; ++it) {
        int o = tid + it * 256;
        int z = o >> 6, y = (o >> 3) & 7, x = o & 7;
        float m[5];
#pragma unroll
        for (int c = 0; c < 5; ++c) {
            const float* src = &t2[c * 896 + z * 112 + y * IN + x];
            float s = 0.f;
#pragma unroll
            for (int k = 0; k < 7; ++k) s += W[k] * src[k];
            m[c] = s;
        }
        float mp = m[0], mt = m[1];
        float mp2 = mp * mp, mt2 = mt * mt, mpt = mp * mt;
        float num = (2.f * mpt + C1) * (2.f * (m[4] - mpt) + C2);
        float den = (mp2 + mt2 + C1) * ((m[2] - mp2) + (m[3] - mt2) + C2);
        lsum += num / den;
    }

    // ---- block reduction (wave shuffle + LDS), then one f64 atomic ----
#pragma unroll
    for (int off = 32; off > 0; off >>= 1) lsum += __shfl_down(lsum, off);
    float* red = t1;  // region B, no conflict with t2 reads above
    if ((tid & 63) == 0) red[tid >> 6] = lsum;
    __syncthreads();
    if (tid == 0) {
        float bs = red[0] + red[1] + red[2] + red[3];
        atomicAdd(acc, (double)bs);
    }
}

__global__ void ssim_finalize(const double* __restrict__ acc, float* __restrict__ out) {
    if (threadIdx.x == 0 && blockIdx.x == 0)
        out[0] = 1.f - (float)(acc[0] / NVOX_D);
}

extern "C" void kernel_launch(void* const* d_in, const int* in_sizes, int n_in,
                              void* d_out, int out_size, void* d_ws, size_t ws_size,
                              hipStream_t stream) {
    const float* P = (const float*)d_in[0];
    const float* T = (const float*)d_in[1];
    float* out = (float*)d_out;
    double* acc = (double*)d_ws;

    ssim_zero_acc<<<1, 64, 0, stream>>>(acc);
    ssim_main<<<NB * NTILE * NTILE * NTILE, 256, 0, stream>>>(P, T, acc);
    ssim_finalize<<<1, 64, 0, stream>>>(acc, out);
}

// Round 2
// 133.693 us; speedup vs baseline: 3.3901x; 3.3901x over previous
//
#include <hip/hip_runtime.h>

#define DIM 160
#define TY 8
#define TX 32
#define TZ 32
#define HY 14            // TY + 6
#define HX 38            // TX + 6
#define NSL 38           // TZ + 6 input slices per chunk
#define SLICE (HY * HX)  // 532
#define YCN (TY * HX)    // 304
#define NVOX_D 16384000.0

// Gaussian weights, sigma=1.5, size 7
#define W0 0.03663285f
#define W1 0.11128076f
#define W2 0.21674532f
#define W3 0.27068213f

__global__ void ssim_zero_acc(double* acc) {
    if (threadIdx.x == 0 && blockIdx.x == 0) acc[0] = 0.0;
}

__global__ __launch_bounds__(256) void ssim_main(const float* __restrict__ P,
                                                 const float* __restrict__ T,
                                                 double* __restrict__ acc) {
    const float W[7] = {W0, W1, W2, W3, W2, W1, W0};

    __shared__ float sP[2 * SLICE];   // double-buffered input plane (p)
    __shared__ float sT[2 * SLICE];   // double-buffered input plane (t)
    __shared__ float yc[5 * YCN];     // after y-conv: [ch][8][38]
    __shared__ float red[4];

    const int tid = threadIdx.x;
    int bid = blockIdx.x;
    int b   = bid / 500;              // 5 zc * 20 ty * 5 tx
    int r   = bid - b * 500;
    int zc  = r / 100;
    int r2  = r - zc * 100;
    int ty  = r2 / 5;
    int tx  = r2 - ty * 5;

    const int base = b * (DIM * DIM * DIM);
    const int z0 = zc * TZ, y0 = ty * TY - 3, x0 = tx * TX - 3;

    // z-conv partial sums: acc[c][j] accumulates output slice (current-3+j)
    float accz[5][7];
#pragma unroll
    for (int c = 0; c < 5; ++c)
#pragma unroll
        for (int j = 0; j < 7; ++j) accz[c][j] = 0.f;
    float lsum = 0.f;

    // ---- prologue: load slice i=0 (zs = z0-3) into buffer 0 ----
    {
        int zs = z0 - 3;
        bool zok = (unsigned)zs < (unsigned)DIM;
        for (int u = tid; u < SLICE; u += 256) {
            int y = u / HX, x = u - y * HX;
            int gy = y0 + y, gx = x0 + x;
            bool ok = zok & ((unsigned)gy < (unsigned)DIM) & ((unsigned)gx < (unsigned)DIM);
            int gi = base + (zs * DIM + gy) * DIM + gx;
            sP[u] = ok ? P[gi] : 0.f;
            sT[u] = ok ? T[gi] : 0.f;
        }
    }
    __syncthreads();

    const int cy = tid >> 5, cx = tid & 31;   // this thread's output column

    for (int i = 0; i < NSL; ++i) {
        const float* cP = sP + (i & 1) * SLICE;
        const float* cT = sT + (i & 1) * SLICE;

        // ---- y-conv: 304 sites, 5 channels per sweep ----
        for (int u = tid; u < YCN; u += 256) {
            int y = u / HX, x = u - y * HX;
            float s0 = 0.f, s1 = 0.f, s2 = 0.f, s3 = 0.f, s4 = 0.f;
#pragma unroll
            for (int k = 0; k < 7; ++k) {
                float w = W[k];
                float p = cP[(y + k) * HX + x];
                float t = cT[(y + k) * HX + x];
                s0 = fmaf(w, p, s0);
                s1 = fmaf(w, t, s1);
                float wp = w * p, wt = w * t;
                s2 = fmaf(wp, p, s2);
                s3 = fmaf(wt, t, s3);
                s4 = fmaf(wp, t, s4);
            }
            yc[u]           = s0;
            yc[u + YCN]     = s1;
            yc[u + 2 * YCN] = s2;
            yc[u + 3 * YCN] = s3;
            yc[u + 4 * YCN] = s4;
        }
        __syncthreads();

        // ---- issue next-slice global loads into regs (hide HBM latency) ----
        float rp0 = 0.f, rt0 = 0.f, rp1 = 0.f, rt1 = 0.f, rp2 = 0.f, rt2 = 0.f;
        const int ii = i + 1;
        if (ii < NSL) {
            int zs = z0 - 3 + ii;
            bool zok = (unsigned)zs < (unsigned)DIM;
            {
                int u = tid, y = u / HX, x = u - y * HX;
                int gy = y0 + y, gx = x0 + x;
                bool ok = zok & ((unsigned)gy < (unsigned)DIM) & ((unsigned)gx < (unsigned)DIM);
                int gi = base + (zs * DIM + gy) * DIM + gx;
                if (ok) { rp0 = P[gi]; rt0 = T[gi]; }
            }
            {
                int u = tid + 256, y = u / HX, x = u - y * HX;
                int gy = y0 + y, gx = x0 + x;
                bool ok = zok & ((unsigned)gy < (unsigned)DIM) & ((unsigned)gx < (unsigned)DIM);
                int gi = base + (zs * DIM + gy) * DIM + gx;
                if (ok) { rp1 = P[gi]; rt1 = T[gi]; }
            }
            if (tid < SLICE - 512) {
                int u = tid + 512, y = u / HX, x = u - y * HX;
                int gy = y0 + y, gx = x0 + x;
                bool ok = zok & ((unsigned)gy < (unsigned)DIM) & ((unsigned)gx < (unsigned)DIM);
                int gi = base + (zs * DIM + gy) * DIM + gx;
                if (ok) { rp2 = P[gi]; rt2 = T[gi]; }
            }
        }

        // ---- x-conv (per-thread column) + z-accumulate + emit ----
        {
            float s[5];
#pragma unroll
            for (int c = 0; c < 5; ++c) {
                const float* src = &yc[c * YCN + cy * HX + cx];
                float v = 0.f;
#pragma unroll
                for (int k = 0; k < 7; ++k) v = fmaf(W[k], src[k], v);
                s[c] = v;
            }
#pragma unroll
            for (int c = 0; c < 5; ++c) {
                accz[c][0] = fmaf(W0, s[c], accz[c][0]);  // W[6-j], j=0 -> W[6]=W0
                accz[c][1] = fmaf(W1, s[c], accz[c][1]);
                accz[c][2] = fmaf(W2, s[c], accz[c][2]);
                accz[c][3] = fmaf(W3, s[c], accz[c][3]);
                accz[c][4] = fmaf(W2, s[c], accz[c][4]);
                accz[c][5] = fmaf(W1, s[c], accz[c][5]);
                accz[c][6] = fmaf(W0, s[c], accz[c][6]);
            }
            if (i >= 6) {
                float mp = accz[0][0], mt = accz[1][0];
                float mp2 = mp * mp, mt2 = mt * mt, mpt = mp * mt;
                float num = (2.f * mpt + 1e-4f) * (2.f * (accz[4][0] - mpt) + 9e-4f);
                float den = (mp2 + mt2 + 1e-4f) *
                            ((accz[2][0] - mp2) + (accz[3][0] - mt2) + 9e-4f);
                lsum += num / den;
            }
#pragma unroll
            for (int c = 0; c < 5; ++c) {
#pragma unroll
                for (int j = 0; j < 6; ++j) accz[c][j] = accz[c][j + 1];
                accz[c][6] = 0.f;
            }
        }

        // ---- write next slice into the other buffer ----
        if (ii < NSL) {
            float* nP = sP + (ii & 1) * SLICE;
            float* nT = sT + (ii & 1) * SLICE;
            nP[tid] = rp0;        nT[tid] = rt0;
            nP[tid + 256] = rp1;  nT[tid + 256] = rt1;
            if (tid < SLICE - 512) { nP[tid + 512] = rp2; nT[tid + 512] = rt2; }
        }
        __syncthreads();
    }

    // ---- block reduction, one f64 atomic ----
#pragma unroll
    for (int off = 32; off > 0; off >>= 1) lsum += __shfl_down(lsum, off);
    if ((tid & 63) == 0) red[tid >> 6] = lsum;
    __syncthreads();
    if (tid == 0) atomicAdd(acc, (double)(red[0] + red[1] + red[2] + red[3]));
}

__global__ void ssim_finalize(const double* __restrict__ acc, float* __restrict__ out) {
    if (threadIdx.x == 0 && blockIdx.x == 0)
        out[0] = 1.f - (float)(acc[0] / NVOX_D);
}

extern "C" void kernel_launch(void* const* d_in, const int* in_sizes, int n_in,
                              void* d_out, int out_size, void* d_ws, size_t ws_size,
                              hipStream_t stream) {
    const float* P = (const float*)d_in[0];
    const float* T = (const float*)d_in[1];
    float* out = (float*)d_out;
    double* acc = (double*)d_ws;

    ssim_zero_acc<<<1, 64, 0, stream>>>(acc);
    ssim_main<<<4 * 5 * 20 * 5, 256, 0, stream>>>(P, T, acc);
    ssim_finalize<<<1, 64, 0, stream>>>(acc, out);
}